// Round 3
// baseline (1252.122 us; speedup 1.0000x reference)
//
#include <hip/hip_runtime.h>

#define NNUE_INPUTS 41024
#define L1N 128
#define L2N 32
#define L3N 32
#define NC_ROW (NNUE_INPUTS / 4)   // 10256 float4 chunks per row
#define MAXK 128                   // per (persp,row) index capacity
#define MAX_ACT 512                // fallback kernel capacity
#define NC_HALF (NC_ROW / 2)
#define WITER 20

typedef float f4 __attribute__((ext_vector_type(4)));
typedef int   i4 __attribute__((ext_vector_type(4)));

__device__ __forceinline__ float clip01(float x) {
    return fminf(fmaxf(x, 0.0f), 1.0f);
}

// Values in w_in/b_in are exactly 0.0f or 1.0f, so integer-OR nonzero
// detect is exact.
__device__ __forceinline__ int nzbits(const f4& x) {
    const i4 b = *(const i4*)&x;
    return (b[0] | b[1]) | (b[2] | b[3]);
}

// ---------------------------------------------------------------------------
// Kernel 0: zero the per-(persp,row) activation counters in workspace.
// ---------------------------------------------------------------------------
__global__ void zero_cnt_kernel(int* __restrict__ cnt, int n) {
    const int i = blockIdx.x * blockDim.x + threadIdx.x;
    if (i < n) cnt[i] = 0;
}

// ---------------------------------------------------------------------------
// Kernel 1: pure streaming scan. Fill-shaped: flat grid-stride over all f4
// chunks of one matrix (blockIdx.y selects w_in / b_in), dense sweeping
// window, no barriers, no per-block row assignment. Rare path (~0.29% of
// lane-chunks) emits indices to workspace via global atomics.
// ---------------------------------------------------------------------------
__global__ __launch_bounds__(256, 8) void scan_kernel(
    const float* __restrict__ w_in, const float* __restrict__ b_in,
    int* __restrict__ cnt, int* __restrict__ idx, int nrows)
{
    const int p = blockIdx.y;                  // 0 = w, 1 = b
    const f4* __restrict__ src = (const f4*)(p ? b_in : w_in);
    int* __restrict__ cntp = cnt + p * nrows;
    int* __restrict__ idxp = idx + (size_t)p * nrows * MAXK;

    const int nch    = nrows * NC_ROW;         // 42,008,576 (fits int)
    const int stride = gridDim.x * blockDim.x; // 524,288

    auto emit = [&](const f4& x, int c) {
        const i4 b = *(const i4*)&x;
        if ((b[0] | b[1]) | (b[2] | b[3])) {
            const int row = c / NC_ROW;                 // magic-mul div
            const int e0  = (c - row * NC_ROW) << 2;
            int* __restrict__ cp = cntp + row;
            int* __restrict__ ip = idxp + row * MAXK;
            if (b[0]) { int q = atomicAdd(cp, 1); ip[q & (MAXK - 1)] = e0;     }
            if (b[1]) { int q = atomicAdd(cp, 1); ip[q & (MAXK - 1)] = e0 + 1; }
            if (b[2]) { int q = atomicAdd(cp, 1); ip[q & (MAXK - 1)] = e0 + 2; }
            if (b[3]) { int q = atomicAdd(cp, 1); ip[q & (MAXK - 1)] = e0 + 3; }
        }
    };

    int c = blockIdx.x * blockDim.x + threadIdx.x;
    for (; c + 3 * stride < nch; c += 4 * stride) {
        const f4 x0 = __builtin_nontemporal_load(src + c);
        const f4 x1 = __builtin_nontemporal_load(src + c + stride);
        const f4 x2 = __builtin_nontemporal_load(src + c + 2 * stride);
        const f4 x3 = __builtin_nontemporal_load(src + c + 3 * stride);
        emit(x0, c);
        emit(x1, c + stride);
        emit(x2, c + 2 * stride);
        emit(x3, c + 3 * stride);
    }
    for (; c < nch; c += stride) {
        const f4 x = __builtin_nontemporal_load(src + c);
        emit(x, c);
    }
}

// ---------------------------------------------------------------------------
// Kernel 2: per-row network eval from compacted indices. One row per block.
// ---------------------------------------------------------------------------
__global__ __launch_bounds__(256, 8) void eval_kernel(
    const float* __restrict__ us, const float* __restrict__ them,
    const float* __restrict__ W_ft, const float* __restrict__ b_ft,
    const float* __restrict__ W1, const float* __restrict__ b1,
    const float* __restrict__ W2, const float* __restrict__ b2,
    const float* __restrict__ Wo, const float* __restrict__ bo,
    const int* __restrict__ cnt, const int* __restrict__ idx,
    float* __restrict__ out, int nrows)
{
    __shared__ int   s_idx[2][MAXK];
    __shared__ float s_w[L1N];
    __shared__ float s_b[L1N];
    __shared__ float s_l0[2 * L1N];
    __shared__ float s_part[8][L2N];
    __shared__ float s_l1[L2N];
    __shared__ float s_l2[L3N];

    const int row = blockIdx.x;
    const int tid = threadIdx.x;

    const int kw = min(cnt[row], MAXK);
    const int kb = min(cnt[nrows + row], MAXK);
    const float u = us[row];
    const float t = them[row];

    // stage index lists to LDS (256 threads load 2*128 ints)
    {
        const int p = tid >> 7;           // 0 or 1
        const int j = tid & (MAXK - 1);
        s_idx[p][j] = idx[((size_t)p * nrows + row) * MAXK + j];
    }
    __syncthreads();

    // ---- gather W_ft rows ----
    {
        const int  ch   = tid & (L1N - 1);
        const bool is_b = tid >= L1N;
        const int* lst  = s_idx[is_b ? 1 : 0];
        const int  K    = is_b ? kb : kw;
        const float* Wc = W_ft + ch;
        float acc = b_ft[ch];
        int k = 0;
        for (; k + 4 <= K; k += 4) {
            const float f0 = Wc[(size_t)lst[k]     * L1N];
            const float f1 = Wc[(size_t)lst[k + 1] * L1N];
            const float f2 = Wc[(size_t)lst[k + 2] * L1N];
            const float f3 = Wc[(size_t)lst[k + 3] * L1N];
            acc += (f0 + f1) + (f2 + f3);
        }
        for (; k < K; ++k) acc += Wc[(size_t)lst[k] * L1N];
        if (is_b) s_b[ch] = acc; else s_w[ch] = acc;
    }
    __syncthreads();

    // ---- perspective mix + clip -> l0 [256] ----
    if (tid < L1N) {
        const float wv = s_w[tid], bv = s_b[tid];
        s_l0[tid]       = clip01(u * wv + t * bv);
        s_l0[L1N + tid] = clip01(u * bv + t * wv);
    }
    __syncthreads();

    // ---- l1 = clip(l0 @ W1 + b1): 8 chunks x 32 outputs ----
    {
        const int o  = tid & 31;
        const int ch = tid >> 5;
        float a = 0.0f;
        const int k0 = ch * 32;
        #pragma unroll
        for (int k = 0; k < 32; ++k) a += s_l0[k0 + k] * W1[(k0 + k) * L2N + o];
        s_part[ch][o] = a;
    }
    __syncthreads();
    if (tid < L2N) {
        float a = b1[tid];
        #pragma unroll
        for (int j = 0; j < 8; ++j) a += s_part[j][tid];
        s_l1[tid] = clip01(a);
    }
    __syncthreads();

    // ---- l2 = clip(l1 @ W2 + b2) ----
    if (tid < L3N) {
        float a = b2[tid];
        #pragma unroll
        for (int k = 0; k < L2N; ++k) a += s_l1[k] * W2[k * L3N + tid];
        s_l2[tid] = clip01(a);
    }
    __syncthreads();

    // ---- out = l2 @ Wo + bo ----
    if (tid == 0) {
        float a = bo[0];
        #pragma unroll
        for (int k = 0; k < L3N; ++k) a += s_l2[k] * Wo[k];
        out[row] = a;
    }
}

// ---------------------------------------------------------------------------
// Fallback: last harness-verified fused kernel (R1, 1206 us). Used when the
// workspace is too small for the split path.
// ---------------------------------------------------------------------------
__global__ __launch_bounds__(256, 6) void nnue_fused_kernel(
    const float* __restrict__ us, const float* __restrict__ them,
    const float* __restrict__ w_in, const float* __restrict__ b_in,
    const float* __restrict__ W_ft, const float* __restrict__ b_ft,
    const float* __restrict__ W1, const float* __restrict__ b1,
    const float* __restrict__ W2, const float* __restrict__ b2,
    const float* __restrict__ Wo, const float* __restrict__ bo,
    float* __restrict__ out)
{
    __shared__ int   s_idx_w[MAX_ACT];
    __shared__ int   s_idx_b[MAX_ACT];
    __shared__ int   s_cnt[2];
    __shared__ float s_w[L1N];
    __shared__ float s_b[L1N];
    __shared__ float s_l0[2 * L1N];
    __shared__ float s_part[8][L2N];
    __shared__ float s_l1[L2N];
    __shared__ float s_l2[L3N];

    const int row  = blockIdx.x;
    const int tid  = threadIdx.x;
    const int wave = tid >> 6;
    const int lane = tid & 63;

    if (tid < 2) s_cnt[tid] = 0;
    const float u = us[row];
    const float t = them[row];
    __syncthreads();

    {
        const int     p    = wave >> 1;
        const f4*     src  = (const f4*)((p ? b_in : w_in) + (size_t)row * NNUE_INPUTS);
        int*          mcnt = &s_cnt[p];
        int*          midx = p ? s_idx_b : s_idx_w;
        const int     base = (wave & 1) * NC_HALF;

        auto emitf4 = [&](const f4& x, int c) {
            const i4 b = *(const i4*)&x;
            const int e = c * 4;
            if (b[0]) { int q = atomicAdd(mcnt, 1); midx[q & (MAX_ACT - 1)] = e;     }
            if (b[1]) { int q = atomicAdd(mcnt, 1); midx[q & (MAX_ACT - 1)] = e + 1; }
            if (b[2]) { int q = atomicAdd(mcnt, 1); midx[q & (MAX_ACT - 1)] = e + 2; }
            if (b[3]) { int q = atomicAdd(mcnt, 1); midx[q & (MAX_ACT - 1)] = e + 3; }
        };

        int c = base + lane;
        f4 x0 = __builtin_nontemporal_load(src + c);
        f4 x1 = __builtin_nontemporal_load(src + c + 64);
        f4 x2 = __builtin_nontemporal_load(src + c + 128);
        f4 x3 = __builtin_nontemporal_load(src + c + 192);
        #pragma unroll 1
        for (int i = 0; i < WITER - 1; ++i) {
            const int cn = c + 256;
            const f4 n0 = __builtin_nontemporal_load(src + cn);
            const f4 n1 = __builtin_nontemporal_load(src + cn + 64);
            const f4 n2 = __builtin_nontemporal_load(src + cn + 128);
            const f4 n3 = __builtin_nontemporal_load(src + cn + 192);
            if (nzbits(x0)) emitf4(x0, c);
            if (nzbits(x1)) emitf4(x1, c + 64);
            if (nzbits(x2)) emitf4(x2, c + 128);
            if (nzbits(x3)) emitf4(x3, c + 192);
            x0 = n0; x1 = n1; x2 = n2; x3 = n3;
            c = cn;
        }
        if (nzbits(x0)) emitf4(x0, c);
        if (nzbits(x1)) emitf4(x1, c + 64);
        if (nzbits(x2)) emitf4(x2, c + 128);
        if (nzbits(x3)) emitf4(x3, c + 192);
        if (lane < NC_HALF - WITER * 256) {
            const int ct = base + WITER * 256 + lane;
            const f4 x = __builtin_nontemporal_load(src + ct);
            if (nzbits(x)) emitf4(x, ct);
        }
    }
    __syncthreads();

    const int kw = min(s_cnt[0], MAX_ACT);
    const int kb = min(s_cnt[1], MAX_ACT);

    {
        const int  ch   = tid & (L1N - 1);
        const bool is_b = tid >= L1N;
        const int* lst  = is_b ? s_idx_b : s_idx_w;
        const int  K    = is_b ? kb : kw;
        const float* Wc = W_ft + ch;
        float acc = b_ft[ch];
        int k = 0;
        for (; k + 4 <= K; k += 4) {
            const float f0 = Wc[(size_t)lst[k]     * L1N];
            const float f1 = Wc[(size_t)lst[k + 1] * L1N];
            const float f2 = Wc[(size_t)lst[k + 2] * L1N];
            const float f3 = Wc[(size_t)lst[k + 3] * L1N];
            acc += (f0 + f1) + (f2 + f3);
        }
        for (; k < K; ++k) acc += Wc[(size_t)lst[k] * L1N];
        if (is_b) s_b[ch] = acc; else s_w[ch] = acc;
    }
    __syncthreads();

    if (tid < L1N) {
        const float wv = s_w[tid], bv = s_b[tid];
        s_l0[tid]       = clip01(u * wv + t * bv);
        s_l0[L1N + tid] = clip01(u * bv + t * wv);
    }
    __syncthreads();

    {
        const int o  = tid & 31;
        const int ch = tid >> 5;
        float a = 0.0f;
        const int k0 = ch * 32;
        #pragma unroll
        for (int k = 0; k < 32; ++k) a += s_l0[k0 + k] * W1[(k0 + k) * L2N + o];
        s_part[ch][o] = a;
    }
    __syncthreads();
    if (tid < L2N) {
        float a = b1[tid];
        #pragma unroll
        for (int j = 0; j < 8; ++j) a += s_part[j][tid];
        s_l1[tid] = clip01(a);
    }
    __syncthreads();

    if (tid < L3N) {
        float a = b2[tid];
        #pragma unroll
        for (int k = 0; k < L2N; ++k) a += s_l1[k] * W2[k * L3N + tid];
        s_l2[tid] = clip01(a);
    }
    __syncthreads();

    if (tid == 0) {
        float a = bo[0];
        #pragma unroll
        for (int k = 0; k < L3N; ++k) a += s_l2[k] * Wo[k];
        out[row] = a;
    }
}

extern "C" void kernel_launch(void* const* d_in, const int* in_sizes, int n_in,
                              void* d_out, int out_size, void* d_ws, size_t ws_size,
                              hipStream_t stream) {
    const float* us   = (const float*)d_in[0];
    const float* them = (const float*)d_in[1];
    const float* w_in = (const float*)d_in[2];
    const float* b_in = (const float*)d_in[3];
    const float* W_ft = (const float*)d_in[4];
    const float* b_ft = (const float*)d_in[5];
    const float* W1   = (const float*)d_in[6];
    const float* b1   = (const float*)d_in[7];
    const float* W2   = (const float*)d_in[8];
    const float* b2   = (const float*)d_in[9];
    const float* Wo   = (const float*)d_in[10];
    const float* bo   = (const float*)d_in[11];
    float* out = (float*)d_out;

    const int B = in_sizes[0];  // 4096

    // workspace layout: cnt[2*B] ints, then idx[2*B*MAXK] ints (~4.2 MB)
    const size_t need = ((size_t)2 * B + (size_t)2 * B * MAXK) * sizeof(int);
    if (d_ws != nullptr && ws_size >= need) {
        int* cnt = (int*)d_ws;
        int* idx = cnt + 2 * B;
        zero_cnt_kernel<<<dim3((2 * B + 255) / 256), dim3(256), 0, stream>>>(cnt, 2 * B);
        scan_kernel<<<dim3(2048, 2), dim3(256), 0, stream>>>(w_in, b_in, cnt, idx, B);
        eval_kernel<<<dim3(B), dim3(256), 0, stream>>>(
            us, them, W_ft, b_ft, W1, b1, W2, b2, Wo, bo, cnt, idx, out, B);
    } else {
        nnue_fused_kernel<<<dim3(B), dim3(256), 0, stream>>>(
            us, them, w_in, b_in, W_ft, b_ft, W1, b1, W2, b2, Wo, bo, out);
    }
}

// Round 4
// 1246.418 us; speedup vs baseline: 1.0046x; 1.0046x over previous
//
#include <hip/hip_runtime.h>

#define NNUE_INPUTS 41024
#define L1N 128
#define L2N 32
#define L3N 32
#define NC_ROW (NNUE_INPUTS / 4)   // 10256 float4 chunks per row
#define MAXK 128                   // per (persp,row) index capacity
#define MAX_ACT 512                // fallback kernel capacity
#define NC_HALF (NC_ROW / 2)
#define WITER 20

typedef float f4 __attribute__((ext_vector_type(4)));
typedef int   i4 __attribute__((ext_vector_type(4)));

__device__ __forceinline__ float clip01(float x) {
    return fminf(fmaxf(x, 0.0f), 1.0f);
}

// Values in w_in/b_in are exactly 0.0f or 1.0f, so integer-OR nonzero
// detect is exact.
__device__ __forceinline__ int nzbits(const f4& x) {
    const i4 b = *(const i4*)&x;
    return (b[0] | b[1]) | (b[2] | b[3]);
}

// ---------------------------------------------------------------------------
// Kernel 0: zero the per-(persp,row) activation counters in workspace.
// ---------------------------------------------------------------------------
__global__ void zero_cnt_kernel(int* __restrict__ cnt, int n) {
    const int i = blockIdx.x * blockDim.x + threadIdx.x;
    if (i < n) cnt[i] = 0;
}

// ---------------------------------------------------------------------------
// Kernel 1: pure streaming scan, SOFTWARE-PIPELINED DEPTH 8.
// Single variable vs R3: while batch i is being consumed, batch i+1's four
// dwordx4 loads are already in flight (steady-state s_waitcnt vmcnt(4),
// never drained to 0 inside the loop). Tests H1 (per-wave MLP limit) vs
// H2 (per-CU outstanding-read cap).
// ---------------------------------------------------------------------------
__global__ __launch_bounds__(256, 8) void scan_kernel(
    const float* __restrict__ w_in, const float* __restrict__ b_in,
    int* __restrict__ cnt, int* __restrict__ idx, int nrows)
{
    const int p = blockIdx.y;                  // 0 = w, 1 = b
    const f4* __restrict__ src = (const f4*)(p ? b_in : w_in);
    int* __restrict__ cntp = cnt + p * nrows;
    int* __restrict__ idxp = idx + (size_t)p * nrows * MAXK;

    const int nch    = nrows * NC_ROW;         // 42,008,576 (fits int)
    const int s      = gridDim.x * blockDim.x; // 524,288

    auto emit = [&](const f4& x, int c) {
        const i4 b = *(const i4*)&x;
        if ((b[0] | b[1]) | (b[2] | b[3])) {
            const int row = c / NC_ROW;                 // magic-mul div
            const int e0  = (c - row * NC_ROW) << 2;
            int* __restrict__ cp = cntp + row;
            int* __restrict__ ip = idxp + row * MAXK;
            if (b[0]) { int q = atomicAdd(cp, 1); ip[q & (MAXK - 1)] = e0;     }
            if (b[1]) { int q = atomicAdd(cp, 1); ip[q & (MAXK - 1)] = e0 + 1; }
            if (b[2]) { int q = atomicAdd(cp, 1); ip[q & (MAXK - 1)] = e0 + 2; }
            if (b[3]) { int q = atomicAdd(cp, 1); ip[q & (MAXK - 1)] = e0 + 3; }
        }
    };

    int c = blockIdx.x * blockDim.x + threadIdx.x;

    if (c + 3 * s < nch) {                     // at least one full batch
        f4 a0 = __builtin_nontemporal_load(src + c);
        f4 a1 = __builtin_nontemporal_load(src + c + s);
        f4 a2 = __builtin_nontemporal_load(src + c + 2 * s);
        f4 a3 = __builtin_nontemporal_load(src + c + 3 * s);
        #pragma unroll 1
        while (c + 7 * s < nch) {              // next full batch exists
            const int cn = c + 4 * s;
            const f4 b0 = __builtin_nontemporal_load(src + cn);
            const f4 b1 = __builtin_nontemporal_load(src + cn + s);
            const f4 b2 = __builtin_nontemporal_load(src + cn + 2 * s);
            const f4 b3 = __builtin_nontemporal_load(src + cn + 3 * s);
            emit(a0, c);
            emit(a1, c + s);
            emit(a2, c + 2 * s);
            emit(a3, c + 3 * s);
            a0 = b0; a1 = b1; a2 = b2; a3 = b3;
            c = cn;
        }
        emit(a0, c);
        emit(a1, c + s);
        emit(a2, c + 2 * s);
        emit(a3, c + 3 * s);
        c += 4 * s;
    }
    for (; c < nch; c += s) {                  // remainder singles
        const f4 x = __builtin_nontemporal_load(src + c);
        emit(x, c);
    }
}

// ---------------------------------------------------------------------------
// Kernel 2: per-row network eval from compacted indices. One row per block.
// ---------------------------------------------------------------------------
__global__ __launch_bounds__(256, 8) void eval_kernel(
    const float* __restrict__ us, const float* __restrict__ them,
    const float* __restrict__ W_ft, const float* __restrict__ b_ft,
    const float* __restrict__ W1, const float* __restrict__ b1,
    const float* __restrict__ W2, const float* __restrict__ b2,
    const float* __restrict__ Wo, const float* __restrict__ bo,
    const int* __restrict__ cnt, const int* __restrict__ idx,
    float* __restrict__ out, int nrows)
{
    __shared__ int   s_idx[2][MAXK];
    __shared__ float s_w[L1N];
    __shared__ float s_b[L1N];
    __shared__ float s_l0[2 * L1N];
    __shared__ float s_part[8][L2N];
    __shared__ float s_l1[L2N];
    __shared__ float s_l2[L3N];

    const int row = blockIdx.x;
    const int tid = threadIdx.x;

    const int kw = min(cnt[row], MAXK);
    const int kb = min(cnt[nrows + row], MAXK);
    const float u = us[row];
    const float t = them[row];

    // stage index lists to LDS (256 threads load 2*128 ints)
    {
        const int p = tid >> 7;           // 0 or 1
        const int j = tid & (MAXK - 1);
        s_idx[p][j] = idx[((size_t)p * nrows + row) * MAXK + j];
    }
    __syncthreads();

    // ---- gather W_ft rows ----
    {
        const int  ch   = tid & (L1N - 1);
        const bool is_b = tid >= L1N;
        const int* lst  = s_idx[is_b ? 1 : 0];
        const int  K    = is_b ? kb : kw;
        const float* Wc = W_ft + ch;
        float acc = b_ft[ch];
        int k = 0;
        for (; k + 4 <= K; k += 4) {
            const float f0 = Wc[(size_t)lst[k]     * L1N];
            const float f1 = Wc[(size_t)lst[k + 1] * L1N];
            const float f2 = Wc[(size_t)lst[k + 2] * L1N];
            const float f3 = Wc[(size_t)lst[k + 3] * L1N];
            acc += (f0 + f1) + (f2 + f3);
        }
        for (; k < K; ++k) acc += Wc[(size_t)lst[k] * L1N];
        if (is_b) s_b[ch] = acc; else s_w[ch] = acc;
    }
    __syncthreads();

    // ---- perspective mix + clip -> l0 [256] ----
    if (tid < L1N) {
        const float wv = s_w[tid], bv = s_b[tid];
        s_l0[tid]       = clip01(u * wv + t * bv);
        s_l0[L1N + tid] = clip01(u * bv + t * wv);
    }
    __syncthreads();

    // ---- l1 = clip(l0 @ W1 + b1): 8 chunks x 32 outputs ----
    {
        const int o  = tid & 31;
        const int ch = tid >> 5;
        float a = 0.0f;
        const int k0 = ch * 32;
        #pragma unroll
        for (int k = 0; k < 32; ++k) a += s_l0[k0 + k] * W1[(k0 + k) * L2N + o];
        s_part[ch][o] = a;
    }
    __syncthreads();
    if (tid < L2N) {
        float a = b1[tid];
        #pragma unroll
        for (int j = 0; j < 8; ++j) a += s_part[j][tid];
        s_l1[tid] = clip01(a);
    }
    __syncthreads();

    // ---- l2 = clip(l1 @ W2 + b2) ----
    if (tid < L3N) {
        float a = b2[tid];
        #pragma unroll
        for (int k = 0; k < L2N; ++k) a += s_l1[k] * W2[k * L3N + tid];
        s_l2[tid] = clip01(a);
    }
    __syncthreads();

    // ---- out = l2 @ Wo + bo ----
    if (tid == 0) {
        float a = bo[0];
        #pragma unroll
        for (int k = 0; k < L3N; ++k) a += s_l2[k] * Wo[k];
        out[row] = a;
    }
}

// ---------------------------------------------------------------------------
// Fallback: last harness-verified fused kernel (R1, 1206 us). Used when the
// workspace is too small for the split path.
// ---------------------------------------------------------------------------
__global__ __launch_bounds__(256, 6) void nnue_fused_kernel(
    const float* __restrict__ us, const float* __restrict__ them,
    const float* __restrict__ w_in, const float* __restrict__ b_in,
    const float* __restrict__ W_ft, const float* __restrict__ b_ft,
    const float* __restrict__ W1, const float* __restrict__ b1,
    const float* __restrict__ W2, const float* __restrict__ b2,
    const float* __restrict__ Wo, const float* __restrict__ bo,
    float* __restrict__ out)
{
    __shared__ int   s_idx_w[MAX_ACT];
    __shared__ int   s_idx_b[MAX_ACT];
    __shared__ int   s_cnt[2];
    __shared__ float s_w[L1N];
    __shared__ float s_b[L1N];
    __shared__ float s_l0[2 * L1N];
    __shared__ float s_part[8][L2N];
    __shared__ float s_l1[L2N];
    __shared__ float s_l2[L3N];

    const int row  = blockIdx.x;
    const int tid  = threadIdx.x;
    const int wave = tid >> 6;
    const int lane = tid & 63;

    if (tid < 2) s_cnt[tid] = 0;
    const float u = us[row];
    const float t = them[row];
    __syncthreads();

    {
        const int     p    = wave >> 1;
        const f4*     src  = (const f4*)((p ? b_in : w_in) + (size_t)row * NNUE_INPUTS);
        int*          mcnt = &s_cnt[p];
        int*          midx = p ? s_idx_b : s_idx_w;
        const int     base = (wave & 1) * NC_HALF;

        auto emitf4 = [&](const f4& x, int c) {
            const i4 b = *(const i4*)&x;
            const int e = c * 4;
            if (b[0]) { int q = atomicAdd(mcnt, 1); midx[q & (MAX_ACT - 1)] = e;     }
            if (b[1]) { int q = atomicAdd(mcnt, 1); midx[q & (MAX_ACT - 1)] = e + 1; }
            if (b[2]) { int q = atomicAdd(mcnt, 1); midx[q & (MAX_ACT - 1)] = e + 2; }
            if (b[3]) { int q = atomicAdd(mcnt, 1); midx[q & (MAX_ACT - 1)] = e + 3; }
        };

        int c = base + lane;
        f4 x0 = __builtin_nontemporal_load(src + c);
        f4 x1 = __builtin_nontemporal_load(src + c + 64);
        f4 x2 = __builtin_nontemporal_load(src + c + 128);
        f4 x3 = __builtin_nontemporal_load(src + c + 192);
        #pragma unroll 1
        for (int i = 0; i < WITER - 1; ++i) {
            const int cn = c + 256;
            const f4 n0 = __builtin_nontemporal_load(src + cn);
            const f4 n1 = __builtin_nontemporal_load(src + cn + 64);
            const f4 n2 = __builtin_nontemporal_load(src + cn + 128);
            const f4 n3 = __builtin_nontemporal_load(src + cn + 192);
            if (nzbits(x0)) emitf4(x0, c);
            if (nzbits(x1)) emitf4(x1, c + 64);
            if (nzbits(x2)) emitf4(x2, c + 128);
            if (nzbits(x3)) emitf4(x3, c + 192);
            x0 = n0; x1 = n1; x2 = n2; x3 = n3;
            c = cn;
        }
        if (nzbits(x0)) emitf4(x0, c);
        if (nzbits(x1)) emitf4(x1, c + 64);
        if (nzbits(x2)) emitf4(x2, c + 128);
        if (nzbits(x3)) emitf4(x3, c + 192);
        if (lane < NC_HALF - WITER * 256) {
            const int ct = base + WITER * 256 + lane;
            const f4 x = __builtin_nontemporal_load(src + ct);
            if (nzbits(x)) emitf4(x, ct);
        }
    }
    __syncthreads();

    const int kw = min(s_cnt[0], MAX_ACT);
    const int kb = min(s_cnt[1], MAX_ACT);

    {
        const int  ch   = tid & (L1N - 1);
        const bool is_b = tid >= L1N;
        const int* lst  = is_b ? s_idx_b : s_idx_w;
        const int  K    = is_b ? kb : kw;
        const float* Wc = W_ft + ch;
        float acc = b_ft[ch];
        int k = 0;
        for (; k + 4 <= K; k += 4) {
            const float f0 = Wc[(size_t)lst[k]     * L1N];
            const float f1 = Wc[(size_t)lst[k + 1] * L1N];
            const float f2 = Wc[(size_t)lst[k + 2] * L1N];
            const float f3 = Wc[(size_t)lst[k + 3] * L1N];
            acc += (f0 + f1) + (f2 + f3);
        }
        for (; k < K; ++k) acc += Wc[(size_t)lst[k] * L1N];
        if (is_b) s_b[ch] = acc; else s_w[ch] = acc;
    }
    __syncthreads();

    if (tid < L1N) {
        const float wv = s_w[tid], bv = s_b[tid];
        s_l0[tid]       = clip01(u * wv + t * bv);
        s_l0[L1N + tid] = clip01(u * bv + t * wv);
    }
    __syncthreads();

    {
        const int o  = tid & 31;
        const int ch = tid >> 5;
        float a = 0.0f;
        const int k0 = ch * 32;
        #pragma unroll
        for (int k = 0; k < 32; ++k) a += s_l0[k0 + k] * W1[(k0 + k) * L2N + o];
        s_part[ch][o] = a;
    }
    __syncthreads();
    if (tid < L2N) {
        float a = b1[tid];
        #pragma unroll
        for (int j = 0; j < 8; ++j) a += s_part[j][tid];
        s_l1[tid] = clip01(a);
    }
    __syncthreads();

    if (tid < L3N) {
        float a = b2[tid];
        #pragma unroll
        for (int k = 0; k < L2N; ++k) a += s_l1[k] * W2[k * L3N + tid];
        s_l2[tid] = clip01(a);
    }
    __syncthreads();

    if (tid == 0) {
        float a = bo[0];
        #pragma unroll
        for (int k = 0; k < L3N; ++k) a += s_l2[k] * Wo[k];
        out[row] = a;
    }
}

extern "C" void kernel_launch(void* const* d_in, const int* in_sizes, int n_in,
                              void* d_out, int out_size, void* d_ws, size_t ws_size,
                              hipStream_t stream) {
    const float* us   = (const float*)d_in[0];
    const float* them = (const float*)d_in[1];
    const float* w_in = (const float*)d_in[2];
    const float* b_in = (const float*)d_in[3];
    const float* W_ft = (const float*)d_in[4];
    const float* b_ft = (const float*)d_in[5];
    const float* W1   = (const float*)d_in[6];
    const float* b1   = (const float*)d_in[7];
    const float* W2   = (const float*)d_in[8];
    const float* b2   = (const float*)d_in[9];
    const float* Wo   = (const float*)d_in[10];
    const float* bo   = (const float*)d_in[11];
    float* out = (float*)d_out;

    const int B = in_sizes[0];  // 4096

    // workspace layout: cnt[2*B] ints, then idx[2*B*MAXK] ints (~4.2 MB)
    const size_t need = ((size_t)2 * B + (size_t)2 * B * MAXK) * sizeof(int);
    if (d_ws != nullptr && ws_size >= need) {
        int* cnt = (int*)d_ws;
        int* idx = cnt + 2 * B;
        zero_cnt_kernel<<<dim3((2 * B + 255) / 256), dim3(256), 0, stream>>>(cnt, 2 * B);
        scan_kernel<<<dim3(2048, 2), dim3(256), 0, stream>>>(w_in, b_in, cnt, idx, B);
        eval_kernel<<<dim3(B), dim3(256), 0, stream>>>(
            us, them, W_ft, b_ft, W1, b1, W2, b2, Wo, bo, cnt, idx, out, B);
    } else {
        nnue_fused_kernel<<<dim3(B), dim3(256), 0, stream>>>(
            us, them, w_in, b_in, W_ft, b_ft, W1, b1, W2, b2, Wo, bo, out);
    }
}